// Round 1
// baseline (1819.051 us; speedup 1.0000x reference)
//
#include <hip/hip_runtime.h>
#include <hip/hip_bf16.h>

#define TT 2048   // tokens
#define HH 2048   // hidden
#define EE 32     // experts
#define II 768    // intermediate
#define KTOP 8

typedef unsigned short u16;
typedef __bf16 bf16x8 __attribute__((ext_vector_type(8)));
typedef float f32x4 __attribute__((ext_vector_type(4)));
typedef unsigned short u16x8 __attribute__((ext_vector_type(8)));

__device__ __forceinline__ u16 f2b(float f) {
    union { float f; unsigned int u; } v; v.f = f;
    unsigned int r = v.u + 0x7fffu + ((v.u >> 16) & 1u);  // RNE
    return (u16)(r >> 16);
}

// load 16 consecutive fp32, convert to bf16, store 32B to LDS
__device__ __forceinline__ void cvt16(const float* __restrict__ src, u16* __restrict__ dst) {
    const float4* s = reinterpret_cast<const float4*>(src);
    float4 f0 = s[0], f1 = s[1], f2 = s[2], f3 = s[3];
    u16x8 a, b;
    a[0] = f2b(f0.x); a[1] = f2b(f0.y); a[2] = f2b(f0.z); a[3] = f2b(f0.w);
    a[4] = f2b(f1.x); a[5] = f2b(f1.y); a[6] = f2b(f1.z); a[7] = f2b(f1.w);
    b[0] = f2b(f2.x); b[1] = f2b(f2.y); b[2] = f2b(f2.z); b[3] = f2b(f2.w);
    b[4] = f2b(f3.x); b[5] = f2b(f3.y); b[6] = f2b(f3.z); b[7] = f2b(f3.w);
    *reinterpret_cast<u16x8*>(dst)     = a;
    *reinterpret_cast<u16x8*>(dst + 8) = b;
}

__global__ void cast_hs_kernel(const float* __restrict__ in, u16* __restrict__ out) {
    int i = (blockIdx.x * 256 + threadIdx.x) * 4;
    float4 v = *reinterpret_cast<const float4*>(in + i);
    union { u16 s[4]; uint2 v; } o;
    o.s[0] = f2b(v.x); o.s[1] = f2b(v.y); o.s[2] = f2b(v.z); o.s[3] = f2b(v.w);
    *reinterpret_cast<uint2*>(out + i) = o.v;
}

// one wave per token: logits -> softmax -> top8 -> renorm -> append to expert lists
__global__ void router_kernel(const float* __restrict__ hs, const float* __restrict__ gw,
                              int* __restrict__ counts, int* __restrict__ tok_id,
                              float* __restrict__ tok_w) {
    const int t = blockIdx.x;
    const int lane = threadIdx.x;
    float x[32];
#pragma unroll
    for (int j = 0; j < 32; j++) x[j] = hs[(size_t)t * HH + lane + 64 * j];
    __shared__ float logits[EE];
    for (int e = 0; e < EE; e++) {
        const float* w = gw + (size_t)e * HH;
        float acc = 0.f;
#pragma unroll
        for (int j = 0; j < 32; j++) acc += x[j] * w[lane + 64 * j];
#pragma unroll
        for (int off = 32; off > 0; off >>= 1) acc += __shfl_down(acc, off);
        if (lane == 0) logits[e] = acc;
    }
    __syncthreads();
    if (lane == 0) {
        float mx = logits[0];
        for (int e = 1; e < EE; e++) mx = fmaxf(mx, logits[e]);
        float p[EE];
        for (int e = 0; e < EE; e++) p[e] = expf(logits[e] - mx);
        int sel[KTOP]; float sw[KTOP]; float ssum = 0.f;
        for (int k = 0; k < KTOP; k++) {
            float best = -1.f; int bi = 0;
            for (int e = 0; e < EE; e++) { if (p[e] > best) { best = p[e]; bi = e; } }
            sel[k] = bi; sw[k] = best; ssum += best; p[bi] = -2.f;  // mark used
        }
        const float inv = 1.f / ssum;
        for (int k = 0; k < KTOP; k++) {
            const int e = sel[k];
            const int slot = atomicAdd(&counts[e], 1);
            tok_id[e * TT + slot] = t;
            tok_w[e * TT + slot] = sw[k] * inv;
        }
    }
}

__global__ void offsets_kernel(const int* __restrict__ counts, int* __restrict__ offsets) {
    if (threadIdx.x == 0 && blockIdx.x == 0) {
        int s = 0;
        for (int e = 0; e < EE; e++) { offsets[e] = s; s += counts[e]; }
        offsets[EE] = s;
    }
}

// grouped GEMM: [cnt x 2048] @ [64 x 2048]^T twice (gate+up), SiLU*up*w fused, -> a_buf bf16
__global__ __launch_bounds__(256) void gateup_kernel(
    const u16* __restrict__ hsb, const float* __restrict__ w_gate,
    const float* __restrict__ w_up, const int* __restrict__ counts,
    const int* __restrict__ offsets, const int* __restrict__ tok_id,
    const float* __restrict__ tok_w, u16* __restrict__ a_buf) {
    const int e = blockIdx.z, it = blockIdx.y, tt = blockIdx.x;
    const int cnt = counts[e];
    if (tt * 128 >= cnt) return;
    __shared__ u16 As[128][40];  // stride 40 (80B): 16B frag reads -> 2-way banks (free)
    __shared__ u16 Bg[64][40];
    __shared__ u16 Bu[64][40];
    const int tid = threadIdx.x;

    // A staging setup: thread -> (row, half of 32 cols)
    const int ar = tid >> 1, ahf = tid & 1;
    int aslot = tt * 128 + ar; if (aslot >= cnt) aslot = cnt - 1;  // clamp: tok_id garbage beyond cnt
    const int tok = tok_id[e * TT + aslot];
    const int4* aptr = reinterpret_cast<const int4*>(hsb + (size_t)tok * HH);
    // B staging: tid<128 -> gate rows, tid>=128 -> up rows
    const int br = (tid & 127) >> 1, bhf = tid & 1;
    const float* bsrc = ((tid < 128) ? w_gate : w_up)
                        + ((size_t)e * II + it * 64 + br) * HH + bhf * 16;
    u16* bdst = (tid < 128) ? &Bg[br][bhf * 16] : &Bu[br][bhf * 16];

    f32x4 accg[4][2], accu[4][2];
#pragma unroll
    for (int i = 0; i < 4; i++)
#pragma unroll
        for (int j = 0; j < 2; j++) {
            accg[i][j] = (f32x4){0.f, 0.f, 0.f, 0.f};
            accu[i][j] = (f32x4){0.f, 0.f, 0.f, 0.f};
        }

    const int wid = tid >> 6, lane = tid & 63;
    const int wm = (wid & 1) * 64, wn = (wid >> 1) * 32;
    const int ml = lane & 15, q = lane >> 4;

    for (int k0 = 0; k0 < HH; k0 += 32) {
        __syncthreads();
        int4 av0 = aptr[(k0 >> 3) + ahf * 2];
        int4 av1 = aptr[(k0 >> 3) + ahf * 2 + 1];
        *reinterpret_cast<int4*>(&As[ar][ahf * 16])     = av0;
        *reinterpret_cast<int4*>(&As[ar][ahf * 16 + 8]) = av1;
        cvt16(bsrc + k0, bdst);
        __syncthreads();

        bf16x8 af[4];
#pragma unroll
        for (int mi = 0; mi < 4; mi++)
            af[mi] = *reinterpret_cast<const bf16x8*>(&As[wm + mi * 16 + ml][q * 8]);
#pragma unroll
        for (int ni = 0; ni < 2; ni++) {
            bf16x8 bg = *reinterpret_cast<const bf16x8*>(&Bg[wn + ni * 16 + ml][q * 8]);
            bf16x8 bu = *reinterpret_cast<const bf16x8*>(&Bu[wn + ni * 16 + ml][q * 8]);
#pragma unroll
            for (int mi = 0; mi < 4; mi++) {
                accg[mi][ni] = __builtin_amdgcn_mfma_f32_16x16x32_bf16(af[mi], bg, accg[mi][ni], 0, 0, 0);
                accu[mi][ni] = __builtin_amdgcn_mfma_f32_16x16x32_bf16(af[mi], bu, accu[mi][ni], 0, 0, 0);
            }
        }
    }

    const int obase = offsets[e];
#pragma unroll
    for (int mi = 0; mi < 4; mi++) {
#pragma unroll
        for (int reg = 0; reg < 4; reg++) {
            const int row = tt * 128 + wm + mi * 16 + q * 4 + reg;
            if (row < cnt) {
                const float w = tok_w[e * TT + row];
#pragma unroll
                for (int ni = 0; ni < 2; ni++) {
                    float g = accg[mi][ni][reg];
                    float u = accu[mi][ni][reg];
                    float a = (g / (1.f + expf(-g))) * u * w;  // silu(g)*u, routing weight folded in
                    a_buf[(size_t)(obase + row) * II + it * 64 + wn + ni * 16 + ml] = f2b(a);
                }
            }
        }
    }
}

// grouped GEMM: [cnt x 768] @ [128 x 768]^T -> atomicAdd scatter into out
__global__ __launch_bounds__(256) void down_kernel(
    const u16* __restrict__ a_buf, const float* __restrict__ w_down,
    const int* __restrict__ counts, const int* __restrict__ offsets,
    const int* __restrict__ tok_id, float* __restrict__ out) {
    const int e = blockIdx.z, ht = blockIdx.y, tt = blockIdx.x;
    const int cnt = counts[e];
    if (tt * 128 >= cnt) return;
    __shared__ u16 As[128][40];
    __shared__ u16 Bd[128][40];
    const int tid = threadIdx.x;
    const int r = tid >> 1, hf = tid & 1;
    int aslot = tt * 128 + r; if (aslot >= cnt) aslot = cnt - 1;  // stay inside a_buf
    const int4* aptr = reinterpret_cast<const int4*>(a_buf + (size_t)(offsets[e] + aslot) * II);
    const float* bsrc = w_down + ((size_t)e * HH + ht * 128 + r) * II + hf * 16;

    f32x4 acc[4][4];
#pragma unroll
    for (int i = 0; i < 4; i++)
#pragma unroll
        for (int j = 0; j < 4; j++) acc[i][j] = (f32x4){0.f, 0.f, 0.f, 0.f};

    const int wid = tid >> 6, lane = tid & 63;
    const int wm = (wid & 1) * 64, wn = (wid >> 1) * 64;
    const int ml = lane & 15, q = lane >> 4;

    for (int k0 = 0; k0 < II; k0 += 32) {
        __syncthreads();
        int4 av0 = aptr[(k0 >> 3) + hf * 2];
        int4 av1 = aptr[(k0 >> 3) + hf * 2 + 1];
        *reinterpret_cast<int4*>(&As[r][hf * 16])     = av0;
        *reinterpret_cast<int4*>(&As[r][hf * 16 + 8]) = av1;
        cvt16(bsrc + k0, &Bd[r][hf * 16]);
        __syncthreads();

        bf16x8 af[4];
#pragma unroll
        for (int mi = 0; mi < 4; mi++)
            af[mi] = *reinterpret_cast<const bf16x8*>(&As[wm + mi * 16 + ml][q * 8]);
#pragma unroll
        for (int ni = 0; ni < 4; ni++) {
            bf16x8 bf = *reinterpret_cast<const bf16x8*>(&Bd[wn + ni * 16 + ml][q * 8]);
#pragma unroll
            for (int mi = 0; mi < 4; mi++)
                acc[mi][ni] = __builtin_amdgcn_mfma_f32_16x16x32_bf16(af[mi], bf, acc[mi][ni], 0, 0, 0);
        }
    }

#pragma unroll
    for (int mi = 0; mi < 4; mi++) {
#pragma unroll
        for (int reg = 0; reg < 4; reg++) {
            const int row = tt * 128 + wm + mi * 16 + q * 4 + reg;
            if (row < cnt) {
                const int t = tok_id[e * TT + row];
                float* orow = out + (size_t)t * HH + ht * 128 + wn;
#pragma unroll
                for (int ni = 0; ni < 4; ni++)
                    atomicAdd(&orow[ni * 16 + ml], acc[mi][ni][reg]);
            }
        }
    }
}

extern "C" void kernel_launch(void* const* d_in, const int* in_sizes, int n_in,
                              void* d_out, int out_size, void* d_ws, size_t ws_size,
                              hipStream_t stream) {
    const float* hs     = (const float*)d_in[0];
    const float* gw     = (const float*)d_in[1];
    const float* w_gate = (const float*)d_in[2];
    const float* w_up   = (const float*)d_in[3];
    const float* w_down = (const float*)d_in[4];
    float* out = (float*)d_out;
    char* ws = (char*)d_ws;

    // workspace layout (needs ~42 MB):
    int*   counts  = (int*)ws;                         // 32 ints
    int*   offsets = (int*)(ws + 256);                 // 33 ints
    int*   tok_id  = (int*)(ws + 1024);                // 32*2048 ints  (256 KB)
    float* tok_w   = (float*)(ws + 1024 + EE * TT * 4);// 32*2048 floats (256 KB)
    u16*   hsb     = (u16*)(ws + (1u << 20));          // 2048*2048 bf16 (8 MB)
    u16*   a_buf   = (u16*)(ws + (16u << 20));         // 16384*768 bf16 (25.2 MB)

    hipMemsetAsync(out, 0, (size_t)TT * HH * sizeof(float), stream);
    hipMemsetAsync(counts, 0, EE * sizeof(int), stream);

    cast_hs_kernel<<<(TT * HH) / (256 * 4), 256, 0, stream>>>(hs, hsb);
    router_kernel<<<TT, 64, 0, stream>>>(hs, gw, counts, tok_id, tok_w);
    offsets_kernel<<<1, 64, 0, stream>>>(counts, offsets);
    gateup_kernel<<<dim3(16, II / 64, EE), 256, 0, stream>>>(
        hsb, w_gate, w_up, counts, offsets, tok_id, tok_w, a_buf);
    down_kernel<<<dim3(16, HH / 128, EE), 256, 0, stream>>>(
        a_buf, w_down, counts, offsets, tok_id, out);
}

// Round 2
// 1661.825 us; speedup vs baseline: 1.0946x; 1.0946x over previous
//
#include <hip/hip_runtime.h>
#include <hip/hip_bf16.h>

#define TT 2048   // tokens
#define HH 2048   // hidden
#define EE 32     // experts
#define II 768    // intermediate
#define KTOP 8

typedef unsigned short u16;
typedef unsigned int u32;
typedef __bf16 bf16x8 __attribute__((ext_vector_type(8)));
typedef float f32x4 __attribute__((ext_vector_type(4)));
typedef unsigned short u16x8 __attribute__((ext_vector_type(8)));

__device__ __forceinline__ u16 f2b(float f) {
    union { float f; unsigned int u; } v; v.f = f;
    unsigned int r = v.u + 0x7fffu + ((v.u >> 16) & 1u);  // RNE
    return (u16)(r >> 16);
}

// async 16B global -> LDS (dest must be wave-uniform base + lane*16)
__device__ __forceinline__ void gl2lds16(const u16* g, u16* l) {
    __builtin_amdgcn_global_load_lds(
        (const __attribute__((address_space(1))) u32*)g,
        (__attribute__((address_space(3))) u32*)l, 16, 0, 0);
}

// generic fp32 -> bf16 cast, 8 elems/thread
__global__ __launch_bounds__(256) void cast_kernel(const float* __restrict__ in,
                                                   u16* __restrict__ out) {
    const size_t i = ((size_t)blockIdx.x * 256 + threadIdx.x) * 8;
    const float4* s = reinterpret_cast<const float4*>(in + i);
    float4 a = s[0], b = s[1];
    union { u16 s[8]; uint4 v; } o;
    o.s[0] = f2b(a.x); o.s[1] = f2b(a.y); o.s[2] = f2b(a.z); o.s[3] = f2b(a.w);
    o.s[4] = f2b(b.x); o.s[5] = f2b(b.y); o.s[6] = f2b(b.z); o.s[7] = f2b(b.w);
    *reinterpret_cast<uint4*>(out + i) = o.v;
}

// one wave per token: logits -> softmax -> top8 -> renorm -> append to expert lists
__global__ void router_kernel(const float* __restrict__ hs, const float* __restrict__ gw,
                              int* __restrict__ counts, int* __restrict__ tok_id,
                              float* __restrict__ tok_w) {
    const int t = blockIdx.x;
    const int lane = threadIdx.x;
    float x[32];
#pragma unroll
    for (int j = 0; j < 32; j++) x[j] = hs[(size_t)t * HH + lane + 64 * j];
    __shared__ float logits[EE];
    for (int e = 0; e < EE; e++) {
        const float* w = gw + (size_t)e * HH;
        float acc = 0.f;
#pragma unroll
        for (int j = 0; j < 32; j++) acc += x[j] * w[lane + 64 * j];
#pragma unroll
        for (int off = 32; off > 0; off >>= 1) acc += __shfl_down(acc, off);
        if (lane == 0) logits[e] = acc;
    }
    __syncthreads();
    if (lane == 0) {
        float mx = logits[0];
        for (int e = 1; e < EE; e++) mx = fmaxf(mx, logits[e]);
        float p[EE];
        for (int e = 0; e < EE; e++) p[e] = expf(logits[e] - mx);
        int sel[KTOP]; float sw[KTOP]; float ssum = 0.f;
        for (int k = 0; k < KTOP; k++) {
            float best = -1.f; int bi = 0;
            for (int e = 0; e < EE; e++) { if (p[e] > best) { best = p[e]; bi = e; } }
            sel[k] = bi; sw[k] = best; ssum += best; p[bi] = -2.f;  // mark used
        }
        const float inv = 1.f / ssum;
        for (int k = 0; k < KTOP; k++) {
            const int e = sel[k];
            const int slot = atomicAdd(&counts[e], 1);
            tok_id[e * TT + slot] = t;
            tok_w[e * TT + slot] = sw[k] * inv;
        }
    }
}

__global__ void offsets_kernel(const int* __restrict__ counts, int* __restrict__ offsets) {
    if (threadIdx.x == 0 && blockIdx.x == 0) {
        int s = 0;
        for (int e = 0; e < EE; e++) { offsets[e] = s; s += counts[e]; }
        offsets[EE] = s;
    }
}

// grouped GEMM: [cnt x 2048] @ [64 x 2048]^T twice (gate+up), SiLU*up*w fused -> a_buf bf16
// m97-style: global_load_lds(16B) staging of bf16, unpadded chunked LDS, 2-barrier K-loop.
__global__ __launch_bounds__(256) void gateup_kernel(
    const u16* __restrict__ hsb, const u16* __restrict__ wgb,
    const u16* __restrict__ wub, const int* __restrict__ counts,
    const int* __restrict__ offsets, const int* __restrict__ tok_id,
    const float* __restrict__ tok_w, u16* __restrict__ a_buf) {
    const int e = blockIdx.z, it = blockIdx.y, tt = blockIdx.x;
    const int cnt = counts[e];
    if (cnt == 0 || tt * 128 >= cnt) return;
    __shared__ u16 As[128 * 32];  // row = 32 u16 = 64B; fragment b128 reads are contiguous 1KB
    __shared__ u16 Bg[64 * 32];
    __shared__ u16 Bu[64 * 32];
    const int tid = threadIdx.x;
    const int wid = tid >> 6, lane = tid & 63;

    // staging: wave w covers rows [16w,16w+16); lane -> (row = 16w + l>>2, 16B chunk = l&3)
    const int srow = (wid << 4) + (lane >> 2);
    const int sc = (lane & 3) << 3;  // col offset in u16
    int aslot0 = tt * 128 + srow;      if (aslot0 >= cnt) aslot0 = cnt - 1;
    int aslot1 = tt * 128 + 64 + srow; if (aslot1 >= cnt) aslot1 = cnt - 1;
    const u16* ag0 = hsb + (size_t)tok_id[e * TT + aslot0] * HH + sc;
    const u16* ag1 = hsb + (size_t)tok_id[e * TT + aslot1] * HH + sc;
    const u16* bgs = wgb + ((size_t)e * II + it * 64 + srow) * HH + sc;
    const u16* bus = wub + ((size_t)e * II + it * 64 + srow) * HH + sc;
    u16* lA0 = As + srow * 32 + sc;         // = As + w*1024B/2 + lane*8  (base + lane*16B)
    u16* lA1 = As + (64 + srow) * 32 + sc;
    u16* lBg = Bg + srow * 32 + sc;
    u16* lBu = Bu + srow * 32 + sc;

    f32x4 accg[4][2], accu[4][2];
#pragma unroll
    for (int i = 0; i < 4; i++)
#pragma unroll
        for (int j = 0; j < 2; j++) {
            accg[i][j] = (f32x4){0.f, 0.f, 0.f, 0.f};
            accu[i][j] = (f32x4){0.f, 0.f, 0.f, 0.f};
        }

    const int wm = (wid & 1) * 64, wn = (wid >> 1) * 32;
    const int ml = lane & 15, q = lane >> 4;

    for (int k0 = 0; k0 < HH; k0 += 32) {
        gl2lds16(ag0 + k0, lA0);
        gl2lds16(ag1 + k0, lA1);
        gl2lds16(bgs + k0, lBg);
        gl2lds16(bus + k0, lBu);
        __syncthreads();  // drains vmcnt(0): LDS image complete

        bf16x8 af[4];
#pragma unroll
        for (int mi = 0; mi < 4; mi++)
            af[mi] = *reinterpret_cast<const bf16x8*>(As + (wm + mi * 16 + ml) * 32 + q * 8);
#pragma unroll
        for (int ni = 0; ni < 2; ni++) {
            bf16x8 bg = *reinterpret_cast<const bf16x8*>(Bg + (wn + ni * 16 + ml) * 32 + q * 8);
            bf16x8 bu = *reinterpret_cast<const bf16x8*>(Bu + (wn + ni * 16 + ml) * 32 + q * 8);
#pragma unroll
            for (int mi = 0; mi < 4; mi++) {
                accg[mi][ni] = __builtin_amdgcn_mfma_f32_16x16x32_bf16(af[mi], bg, accg[mi][ni], 0, 0, 0);
                accu[mi][ni] = __builtin_amdgcn_mfma_f32_16x16x32_bf16(af[mi], bu, accu[mi][ni], 0, 0, 0);
            }
        }
        __syncthreads();  // all waves done reading before next overwrite
    }

    const int obase = offsets[e];
#pragma unroll
    for (int mi = 0; mi < 4; mi++) {
#pragma unroll
        for (int reg = 0; reg < 4; reg++) {
            const int row = tt * 128 + wm + mi * 16 + q * 4 + reg;
            if (row < cnt) {
                const float w = tok_w[e * TT + row];
#pragma unroll
                for (int ni = 0; ni < 2; ni++) {
                    float g = accg[mi][ni][reg];
                    float u = accu[mi][ni][reg];
                    float a = (g / (1.f + expf(-g))) * u * w;  // silu(g)*u, routing weight folded in
                    a_buf[(size_t)(obase + row) * II + it * 64 + wn + ni * 16 + ml] = f2b(a);
                }
            }
        }
    }
}

// grouped GEMM: [cnt x 768] @ [128 x 768]^T -> atomicAdd scatter into out
__global__ __launch_bounds__(256) void down_kernel(
    const u16* __restrict__ a_buf, const u16* __restrict__ wdb,
    const int* __restrict__ counts, const int* __restrict__ offsets,
    const int* __restrict__ tok_id, float* __restrict__ out) {
    const int e = blockIdx.z, ht = blockIdx.y, tt = blockIdx.x;
    const int cnt = counts[e];
    if (cnt == 0 || tt * 128 >= cnt) return;
    __shared__ u16 As[128 * 32];
    __shared__ u16 Bd[128 * 32];
    const int tid = threadIdx.x;
    const int wid = tid >> 6, lane = tid & 63;
    const int srow = (wid << 4) + (lane >> 2);
    const int sc = (lane & 3) << 3;
    int aslot0 = tt * 128 + srow;      if (aslot0 >= cnt) aslot0 = cnt - 1;
    int aslot1 = tt * 128 + 64 + srow; if (aslot1 >= cnt) aslot1 = cnt - 1;
    const u16* ag0 = a_buf + (size_t)(offsets[e] + aslot0) * II + sc;
    const u16* ag1 = a_buf + (size_t)(offsets[e] + aslot1) * II + sc;
    const u16* bs0 = wdb + ((size_t)e * HH + ht * 128 + srow) * II + sc;
    const u16* bs1 = wdb + ((size_t)e * HH + ht * 128 + 64 + srow) * II + sc;
    u16* lA0 = As + srow * 32 + sc;
    u16* lA1 = As + (64 + srow) * 32 + sc;
    u16* lB0 = Bd + srow * 32 + sc;
    u16* lB1 = Bd + (64 + srow) * 32 + sc;

    f32x4 acc[4][4];
#pragma unroll
    for (int i = 0; i < 4; i++)
#pragma unroll
        for (int j = 0; j < 4; j++) acc[i][j] = (f32x4){0.f, 0.f, 0.f, 0.f};

    const int wm = (wid & 1) * 64, wn = (wid >> 1) * 64;
    const int ml = lane & 15, q = lane >> 4;

    for (int k0 = 0; k0 < II; k0 += 32) {
        gl2lds16(ag0 + k0, lA0);
        gl2lds16(ag1 + k0, lA1);
        gl2lds16(bs0 + k0, lB0);
        gl2lds16(bs1 + k0, lB1);
        __syncthreads();

        bf16x8 af[4];
#pragma unroll
        for (int mi = 0; mi < 4; mi++)
            af[mi] = *reinterpret_cast<const bf16x8*>(As + (wm + mi * 16 + ml) * 32 + q * 8);
#pragma unroll
        for (int ni = 0; ni < 4; ni++) {
            bf16x8 bf = *reinterpret_cast<const bf16x8*>(Bd + (wn + ni * 16 + ml) * 32 + q * 8);
#pragma unroll
            for (int mi = 0; mi < 4; mi++)
                acc[mi][ni] = __builtin_amdgcn_mfma_f32_16x16x32_bf16(af[mi], bf, acc[mi][ni], 0, 0, 0);
        }
        __syncthreads();
    }

#pragma unroll
    for (int mi = 0; mi < 4; mi++) {
#pragma unroll
        for (int reg = 0; reg < 4; reg++) {
            const int row = tt * 128 + wm + mi * 16 + q * 4 + reg;
            if (row < cnt) {
                const int t = tok_id[e * TT + row];
                float* orow = out + (size_t)t * HH + ht * 128 + wn;
#pragma unroll
                for (int ni = 0; ni < 4; ni++)
                    atomicAdd(&orow[ni * 16 + ml], acc[mi][ni][reg]);
            }
        }
    }
}

extern "C" void kernel_launch(void* const* d_in, const int* in_sizes, int n_in,
                              void* d_out, int out_size, void* d_ws, size_t ws_size,
                              hipStream_t stream) {
    const float* hs     = (const float*)d_in[0];
    const float* gw     = (const float*)d_in[1];
    const float* w_gate = (const float*)d_in[2];
    const float* w_up   = (const float*)d_in[3];
    const float* w_down = (const float*)d_in[4];
    float* out = (float*)d_out;
    char* ws = (char*)d_ws;

    // workspace layout (~336 MB):
    int*   counts  = (int*)ws;                            // 32 ints
    int*   offsets = (int*)(ws + 256);                    // 33 ints
    int*   tok_id  = (int*)(ws + 1024);                   // 32*2048 ints  (256 KB)
    float* tok_w   = (float*)(ws + 1024 + EE * TT * 4);   // 32*2048 floats (256 KB)
    u16*   hsb     = (u16*)(ws + (1ull << 20));           // 2048*2048 bf16 (8 MB)
    u16*   a_buf   = (u16*)(ws + (16ull << 20));          // 16384*768 bf16 (25.2 MB)
    u16*   wgb     = (u16*)(ws + (48ull << 20));          // 32*768*2048 bf16 (96 MB)
    u16*   wub     = (u16*)(ws + (144ull << 20));         // 96 MB
    u16*   wdb     = (u16*)(ws + (240ull << 20));         // 96 MB

    hipMemsetAsync(out, 0, (size_t)TT * HH * sizeof(float), stream);
    hipMemsetAsync(counts, 0, EE * sizeof(int), stream);

    const int WELEM = EE * II * HH;  // 50,331,648
    cast_kernel<<<WELEM / (256 * 8), 256, 0, stream>>>(w_gate, wgb);
    cast_kernel<<<WELEM / (256 * 8), 256, 0, stream>>>(w_up, wub);
    cast_kernel<<<WELEM / (256 * 8), 256, 0, stream>>>(w_down, wdb);
    cast_kernel<<<(TT * HH) / (256 * 8), 256, 0, stream>>>(hs, hsb);

    router_kernel<<<TT, 64, 0, stream>>>(hs, gw, counts, tok_id, tok_w);
    offsets_kernel<<<1, 64, 0, stream>>>(counts, offsets);

    gateup_kernel<<<dim3(16, II / 64, EE), 256, 0, stream>>>(
        hsb, wgb, wub, counts, offsets, tok_id, tok_w, a_buf);
    down_kernel<<<dim3(16, HH / 128, EE), 256, 0, stream>>>(
        a_buf, wdb, counts, offsets, tok_id, out);
}